// Round 2
// baseline (170.476 us; speedup 1.0000x reference)
//
#include <hip/hip_runtime.h>
#include <stdint.h>

// Problem constants
// x: (8,128,16,16) f32 ; codebook: (4,4096,32) f32 ; temperature: (4,1,1,1)
// rows = (n*4+m)*256 + hw, 8192 rows, K=4096, D=32
// outputs (flat): sample[33554432] code[8192] one_hot[33554432] logit[33554432]

__device__ __forceinline__ uint32_t rotl32(uint32_t x, uint32_t r){
  return (x << r) | (x >> (32u - r));
}

// JAX threefry2x32, key = jax.random.key(42) -> (k1,k2) = (0,42).
// Partitionable random-bits scheme (JAX >= 0.4.36 default):
//   (o0,o1) = threefry2x32((0,42), (hi32(e)=0, lo32(e)=e)); bits = o0 ^ o1
// uniform: u = bitcast((bits>>9)|0x3F800000) - 1, clipped to [eps, 1-eps]
// gumbel:  g = -log(-log(u))
__device__ __forceinline__ float gumbel_from_e(uint32_t e){
  uint32_t x0 = 0u, x1 = e;
  const uint32_t ks0 = 0u, ks1 = 42u, ks2 = 0x1BD11BF0u; // 0 ^ 42 ^ 0x1BD11BDA
  x0 += ks0; x1 += ks1;
#define TFR4(a,b,c,d2) \
  x0 += x1; x1 = rotl32(x1,(a)); x1 ^= x0; \
  x0 += x1; x1 = rotl32(x1,(b)); x1 ^= x0; \
  x0 += x1; x1 = rotl32(x1,(c)); x1 ^= x0; \
  x0 += x1; x1 = rotl32(x1,(d2)); x1 ^= x0;
  TFR4(13,15,26,6)  x0 += ks1; x1 += ks2 + 1u;
  TFR4(17,29,16,24) x0 += ks2; x1 += ks0 + 2u;
  TFR4(13,15,26,6)  x0 += ks0; x1 += ks1 + 3u;
  TFR4(17,29,16,24) x0 += ks1; x1 += ks2 + 4u;
  TFR4(13,15,26,6)  x0 += ks2; x1 += ks0 + 5u;
#undef TFR4
  uint32_t bits = x0 ^ x1;
  float u = __uint_as_float((bits >> 9) | 0x3F800000u) - 1.0f;
  // clip to [2^-23, 1 - 2^-23]  (upper bound = 0x3F7FFFFE exactly, as in ref)
  u = fminf(fmaxf(u, 1.1920929e-07f), __uint_as_float(0x3F7FFFFEu));
  return -logf(-logf(u));
}

// Kernel 1: per block: 32 rows x 256 k tile. Computes logits (written to
// logit_out), online argmax of logit and of logit+gumbel; per-(row,ktile)
// partials stored in first 64 floats of each sample row (overwritten by K2).
__global__ __launch_bounds__(512) void k_logits(
    const float* __restrict__ x, const float* __restrict__ cb,
    const float* __restrict__ temp, float* __restrict__ logit_out,
    float* __restrict__ sample_part){
  __shared__ float xl[32][36];     // 32 rows x 32 d, pad to 36
  __shared__ float cl[9216];       // 256 k x 32 d, stride 36 (conflict-free b128)
  __shared__ float c2l[256];
  __shared__ float x2l[32];

  const int tid = threadIdx.x;
  const int b = blockIdx.x;
  const int kt = b & 15;           // k-tile 0..15
  const int rt = (b >> 4) & 63;    // row-tile 0..63 (within m)
  const int m  = b >> 10;          // 0..3
  const int n  = rt >> 3;
  const int hw0 = (rt & 7) << 5;
  const int k0 = kt << 8;
  const int rowbase = ((n << 2) + m) * 256 + hw0;

  // ---- stage x tile (32 rows x 32 d) ----
  const float* xm = x + ((n * 128 + m * 32) * 256 + hw0);
  #pragma unroll
  for (int i = 0; i < 2; ++i){
    int idx = tid + (i << 9);
    int d = idx >> 5, r = idx & 31;
    xl[r][d] = xm[(d << 8) + r];
  }
  // ---- stage codebook tile (256 k x 32 d) as float4 ----
  const float4* cb4 = (const float4*)(cb + (m * 131072 + k0 * 32));
  #pragma unroll
  for (int i = 0; i < 4; ++i){
    int f = tid + (i << 9);
    float4 v = cb4[f];
    int kk = f >> 3, dq = f & 7;
    *(float4*)&cl[kk * 36 + (dq << 2)] = v;
  }
  __syncthreads();

  // ---- squared norms ----
  if (tid < 256){
    float s = 0.f;
    #pragma unroll
    for (int d = 0; d < 32; ++d){ float c = cl[tid*36 + d]; s = fmaf(c, c, s); }
    c2l[tid] = s;
  }
  if (tid < 32){
    float s = 0.f;
    #pragma unroll
    for (int d = 0; d < 32; ++d){ float v = xl[tid][d]; s = fmaf(v, v, s); }
    x2l[tid] = s;
  }
  __syncthreads();

  // ---- GEMM: each thread 4 rows x 4 ks ----
  const int kg = tid & 63;         // k-group 0..63, ks = kg + 64*j
  const int rg = tid >> 6;         // row-group 0..7 (uniform per wave)
  float acc[4][4];
  #pragma unroll
  for (int i = 0; i < 4; ++i)
    #pragma unroll
    for (int j = 0; j < 4; ++j) acc[i][j] = 0.f;

  #pragma unroll
  for (int dblk = 0; dblk < 8; ++dblk){
    float4 xa[4];
    #pragma unroll
    for (int i = 0; i < 4; ++i)
      xa[i] = *(const float4*)&xl[(rg << 2) + i][dblk << 2];
    #pragma unroll
    for (int j = 0; j < 4; ++j){
      float4 cv = *(const float4*)&cl[(kg + (j << 6)) * 36 + (dblk << 2)];
      #pragma unroll
      for (int i = 0; i < 4; ++i){
        acc[i][j] = fmaf(xa[i].x, cv.x, acc[i][j]);
        acc[i][j] = fmaf(xa[i].y, cv.y, acc[i][j]);
        acc[i][j] = fmaf(xa[i].z, cv.z, acc[i][j]);
        acc[i][j] = fmaf(xa[i].w, cv.w, acc[i][j]);
      }
    }
  }

  // ---- logits + gumbel + per-thread argmax (k ascending -> first-occurrence) ----
  const float tcl = fmaxf(temp[m], 1e-6f);
  float bl[4], bg[4]; int bli[4], bgi[4];
  #pragma unroll
  for (int i = 0; i < 4; ++i){ bl[i] = -INFINITY; bg[i] = -INFINITY; bli[i] = 0; bgi[i] = 0; }

  #pragma unroll
  for (int j = 0; j < 4; ++j){
    const int kk = kg + (j << 6);
    const int k_g = k0 + kk;
    const float c2 = c2l[kk];
    #pragma unroll
    for (int i = 0; i < 4; ++i){
      const int r = (rg << 2) + i;
      const int row_g = rowbase + r;
      float dist = x2l[r] + c2 - 2.0f * acc[i][j];
      float l = (-dist) * 0.015625f * tcl;          // (-dist/64)*t, /64 exact
      logit_out[((size_t)row_g << 12) + k_g] = l;
      float lg = l + gumbel_from_e(((uint32_t)row_g << 12) + (uint32_t)k_g);
      if (l  > bl[i]) { bl[i] = l;  bli[i] = k_g; }
      if (lg > bg[i]) { bg[i] = lg; bgi[i] = k_g; }
    }
  }

  // ---- block reduction over 64 k-groups (reuse cl as scratch) ----
  __syncthreads();                 // all cl reads done
  float* red = cl;                 // 4 arrays of 32*65 floats (pad 65)
  #pragma unroll
  for (int i = 0; i < 4; ++i){
    int r = (rg << 2) + i;
    red[        r * 65 + kg] = bl[i];
    red[2080 +  r * 65 + kg] = __int_as_float(bli[i]);
    red[4160 +  r * 65 + kg] = bg[i];
    red[6240 +  r * 65 + kg] = __int_as_float(bgi[i]);
  }
  __syncthreads();
  if (tid < 64){
    const int r = tid & 31;
    const bool doG = (tid >= 32);
    const int off_v = doG ? 4160 : 0;
    const int off_i = doG ? 6240 : 2080;
    float bv = -INFINITY; int bi = 0;
    for (int g2 = 0; g2 < 64; ++g2){
      float v = red[off_v + r * 65 + g2];
      int  ix = __float_as_int(red[off_i + r * 65 + g2]);
      if (v > bv || (v == bv && ix < bi)){ bv = v; bi = ix; }
    }
    const int row_g = rowbase + r;
    float* part = sample_part + ((size_t)row_g << 12);
    part[(doG ? 32 : 0)  + kt] = bv;
    part[(doG ? 48 : 16) + kt] = __int_as_float(bi);
  }
}

// Kernel 2: one block per row. Reduce the 16 k-tile partials -> code / hard
// index, then zero-fill sample & one_hot rows and scatter the 1.0s.
__global__ __launch_bounds__(256) void k_finalize(
    float* __restrict__ sample, float* __restrict__ code_out,
    float* __restrict__ onehot){
  const int row = blockIdx.x;
  const int tid = threadIdx.x;
  __shared__ int sHard, sCode;
  float* srow = sample + ((size_t)row << 12);
  float* orow = onehot + ((size_t)row << 12);
  if (tid == 0){
    float bLv = -INFINITY, bGv = -INFINITY; int bLi = 0, bGi = 0;
    for (int kt = 0; kt < 16; ++kt){
      float v  = srow[kt];      int ix  = __float_as_int(srow[16 + kt]);
      if (v > bLv || (v == bLv && ix < bLi)){ bLv = v; bLi = ix; }
      float v2 = srow[32 + kt]; int ix2 = __float_as_int(srow[48 + kt]);
      if (v2 > bGv || (v2 == bGv && ix2 < bGi)){ bGv = v2; bGi = ix2; }
    }
    sCode = bLi; sHard = bGi;
    code_out[row] = (float)bLi;   // code stored as f32 (d_out is one f32 buffer)
  }
  __syncthreads();
  const int hard = sHard, codei = sCode;
  const float4 z = make_float4(0.f, 0.f, 0.f, 0.f);
  float4* s4 = (float4*)srow;
  float4* o4 = (float4*)orow;
  #pragma unroll
  for (int i = 0; i < 4; ++i){
    int idx = tid + (i << 8);
    s4[idx] = z;
    o4[idx] = z;
  }
  __syncthreads();
  if (tid == 0){
    srow[hard]  = 1.0f;   // sample = y_hard (off-argmax terms cancel exactly)
    orow[codei] = 1.0f;   // one_hot(argmax(logit))
  }
}

extern "C" void kernel_launch(void* const* d_in, const int* in_sizes, int n_in,
                              void* d_out, int out_size, void* d_ws, size_t ws_size,
                              hipStream_t stream) {
  const float* x    = (const float*)d_in[0];
  const float* cb   = (const float*)d_in[1];
  const float* temp = (const float*)d_in[2];
  float* out    = (float*)d_out;
  float* sample = out;                       // 33554432
  float* code   = out + 33554432;            // 8192
  float* onehot = code + 8192;               // 33554432
  float* logit  = onehot + 33554432;         // 33554432

  hipLaunchKernelGGL(k_logits, dim3(4096), dim3(512), 0, stream,
                     x, cb, temp, logit, sample);
  hipLaunchKernelGGL(k_finalize, dim3(8192), dim3(256), 0, stream,
                     sample, code, onehot);
}